// Round 9
// baseline (261.139 us; speedup 1.0000x reference)
//
#include <hip/hip_runtime.h>
#include <cstddef>
#include <cstdint>

// Problem constants
#define D_MODEL 768
#define N_HEADS 12
#define SEQ 2048
#define BATCH 2
#define NROWS (BATCH * SEQ)          // 4096
#define W_ELEMS (D_MODEL * D_MODEL)  // 589824
#define Y_ELEMS (NROWS * D_MODEL)    // 3145728

typedef __attribute__((ext_vector_type(8))) short bf16x8;
typedef __attribute__((ext_vector_type(4))) float f32x4;

struct TTPtrs {
    const float* c0[4];
    const float* c1[4];
    const float* c2[4];
    const float* c3[4];
};

__device__ __forceinline__ float bf2f(uint16_t u) {
    union { uint32_t u; float f; } c; c.u = ((uint32_t)u) << 16; return c.f;
}
__device__ __forceinline__ uint16_t f2bf(float f) {
    union { float f; uint32_t u; } c; c.f = f;
    uint32_t x = c.u + 0x7fffu + ((c.u >> 16) & 1u);   // RNE
    return (uint16_t)(x >> 16);
}
__device__ __forceinline__ uint32_t cvtpk(float lo, float hi) {
    uint32_t r;
    asm("v_cvt_pk_bf16_f32 %0, %1, %2" : "=v"(r) : "v"(lo), "v"(hi));
    return r;
}
__device__ __forceinline__ void glds16(const void* g, void* l) {
    auto gp = reinterpret_cast<const __attribute__((address_space(1))) uint32_t*>(
        reinterpret_cast<uintptr_t>(g));
    auto lp = reinterpret_cast<__attribute__((address_space(3))) uint32_t*>(
        reinterpret_cast<uintptr_t>(l));
    __builtin_amdgcn_global_load_lds(gp, lp, 16, 0, 0);
}

// Chunk schedule: 40 units per bh, QBLK=128. Unit = (j, c): q-tile j (128 rows),
// k-tiles c*8 .. min(c*8+7, 2j+1). Encoded (j<<2)|c, ordered big-chunks-first.
__device__ const uint8_t UNITS[40] = {
    (3<<2)|0,(4<<2)|0,(5<<2)|0,(6<<2)|0,(7<<2)|0,(7<<2)|1,(8<<2)|0,(8<<2)|1,
    (9<<2)|0,(9<<2)|1,(10<<2)|0,(10<<2)|1,(11<<2)|0,(11<<2)|1,(11<<2)|2,(12<<2)|0,
    (12<<2)|1,(12<<2)|2,(13<<2)|0,(13<<2)|1,(13<<2)|2,(14<<2)|0,(14<<2)|1,(14<<2)|2,
    (15<<2)|0,(15<<2)|1,(15<<2)|2,(15<<2)|3,(2<<2)|0,(6<<2)|1,(10<<2)|2,(14<<2)|3,
    (1<<2)|0,(5<<2)|1,(9<<2)|2,(13<<2)|3,(0<<2)|0,(4<<2)|1,(8<<2)|2,(12<<2)|3};
// Inverse map: UBASE[j*4+c] = unit index
__device__ const uint8_t UBASE[64] = {
    36,0,0,0,  32,0,0,0,  28,0,0,0,  0,0,0,0,
    1,37,0,0,  2,33,0,0,  3,29,0,0,  4,5,0,0,
    6,7,38,0,  8,9,34,0,  10,11,30,0, 12,13,14,0,
    15,16,17,39, 18,19,20,35, 21,22,23,31, 24,25,26,27};

// ---------------------------------------------------------------------------
// pre_kernel: fused buildA (256 blocks) and x -> bf16 conversion (3072 blocks).
// ---------------------------------------------------------------------------
__global__ __launch_bounds__(256) void pre_kernel(TTPtrs P, float* __restrict__ wsA,
                                                  const float* __restrict__ x,
                                                  uint16_t* __restrict__ xb) {
    const int bx = blockIdx.x;
    if (bx < 256) {
        const int mat = bx >> 6;
        const float* c0 = P.c0[mat];
        const float* c1 = P.c1[mat];
        float* A = wsA + mat * 16384;
        int idx = (bx & 63) * 256 + threadIdx.x;
        int s = idx & 63, pj = (idx >> 6) & 15, mi = idx >> 10;
        float acc = 0.f;
        #pragma unroll 8
        for (int r = 0; r < 32; r++)
            acc = fmaf(c0[mi * 32 + r], c1[(r * 16 + pj) * 64 + s], acc);
        A[idx] = acc;
    } else {
        int idx = ((bx - 256) * 256 + threadIdx.x) * 4;
        float4 v = *(const float4*)(x + idx);
        *(uint2*)(xb + idx) = make_uint2(cvtpk(v.x, v.y), cvtpk(v.z, v.w));
    }
}

// Stage B: B[mi][pj][qk][t] = sum_s A * c2, 16*16*36*32 per matrix
__global__ __launch_bounds__(256) void tt_buildB(TTPtrs P, const float* __restrict__ wsA,
                                                 float* __restrict__ wsB) {
    const int mat = blockIdx.y;
    const float* c2 = P.c2[mat];
    const float* A = wsA + mat * 16384;
    float* B = wsB + (size_t)mat * 294912;
    int idx = blockIdx.x * 256 + threadIdx.x;
    int t = idx & 31;
    int rest = idx >> 5;
    int qk = rest % 36;
    int rest2 = rest / 36;
    int pj = rest2 & 15, mi = rest2 >> 4;
    const float* Arow = A + (mi * 16 + pj) * 64;
    float acc = 0.f;
    #pragma unroll 8
    for (int s = 0; s < 64; s++)
        acc = fmaf(Arow[s], c2[(s * 36 + qk) * 32 + t], acc);
    B[idx] = acc;
}

// Stage C: LDS-staged; block = one (mat, mi, pj); 9 outputs/thread.
__global__ __launch_bounds__(256) void tt_buildC(TTPtrs P, const float* __restrict__ wsB,
                                                 uint16_t* __restrict__ Wbf) {
    __shared__ float b_lds[36 * 33];
    __shared__ float c_lds[32 * 64];
    const int mat = blockIdx.y;
    const int mipj = blockIdx.x;
    const int mi = mipj >> 4, pj = mipj & 15;
    const int m = mi >> 2, i = mi & 3, p = pj >> 2, j = pj & 3;
    const float* Bsrc = wsB + (size_t)mat * 294912 + (size_t)mipj * 1152;
    const float* c3 = P.c3[mat];
    uint16_t* Wt = Wbf + (size_t)mat * W_ELEMS;
    const int tid = threadIdx.x;

    for (int e = tid; e < 1152; e += 256) {
        int qk = e >> 5, t = e & 31;
        b_lds[qk * 33 + t] = Bsrc[e];
    }
    for (int e = tid; e < 2048; e += 256)
        c_lds[e] = c3[e];
    __syncthreads();

    const int outbase = (m * 4 + p) * 48;
    const int inbase = (i * 4 + j) * 48;
    #pragma unroll
    for (int n = 0; n < 9; n++) {
        int idx = n * 256 + tid;
        int qu = idx / 48, kl = idx % 48;
        int q = qu >> 3, u = qu & 7, k = kl >> 3, l = kl & 7;
        const float* brow = &b_lds[(q * 6 + k) * 33];
        const float* crow = &c_lds[u * 8 + l];
        float acc = 0.f;
        #pragma unroll 8
        for (int t = 0; t < 32; t++)
            acc = fmaf(brow[t], crow[t * 64], acc);
        Wt[(size_t)(outbase + qu) * D_MODEL + inbase + kl] = f2bf(acc);
    }
}

// ---------------------------------------------------------------------------
// bf16 MFMA GEMM. MODE 0: f32 out. MODE 1: bf16 out; z==2 writes V transposed
// to Vt[b][h][d][s] via LDS-transpose (coalesced 128B runs; old path was 8B
// stores at 4KB stride = ~8x write amplification).
// ---------------------------------------------------------------------------
template <int MODE>
__global__ __launch_bounds__(256) void gemm_mfma(const uint16_t* __restrict__ X,
                                                 const uint16_t* __restrict__ Wall,
                                                 const float* __restrict__ b0,
                                                 const float* __restrict__ b1,
                                                 const float* __restrict__ b2,
                                                 void* __restrict__ Yall,
                                                 uint16_t* __restrict__ Vt) {
    __shared__ uint16_t lds[2][8192];
    const int z = blockIdx.z;
    const uint16_t* W = Wall + (size_t)z * W_ELEMS;
    const float* bias = (z == 0) ? b0 : (z == 1 ? b1 : b2);
    const int m0 = blockIdx.x * 128, n0 = blockIdx.y * 128;
    const int tid = threadIdx.x, w = tid >> 6, l = tid & 63;
    const int wr = w >> 1, wc = w & 1;
    const int l15 = l & 15, lg = l >> 4;

    const int srow = w * 32 + (l >> 2);
    const int scol = ((l & 3) ^ ((l >> 2) & 3)) * 8;
    const uint16_t* Abase = X + (size_t)(m0 + srow) * D_MODEL + scol;
    const uint16_t* Bbase = W + (size_t)(n0 + srow) * D_MODEL + scol;

    f32x4 acc[4][4];
    #pragma unroll
    for (int mi = 0; mi < 4; ++mi)
        #pragma unroll
        for (int ni = 0; ni < 4; ++ni) acc[mi][ni] = (f32x4){0.f, 0.f, 0.f, 0.f};

    auto stage = [&](int buf, int kt) {
        const uint16_t* A0 = Abase + kt * 32;
        const uint16_t* B0 = Bbase + kt * 32;
        glds16(A0, &lds[buf][w * 1024]);
        glds16(A0 + 16 * D_MODEL, &lds[buf][w * 1024 + 512]);
        glds16(B0, &lds[buf][4096 + w * 1024]);
        glds16(B0 + 16 * D_MODEL, &lds[buf][4096 + w * 1024 + 512]);
    };

    stage(0, 0);
    __syncthreads();
    const int roff = ((lg ^ (l & 3)) << 3);
    for (int kt = 0; kt < 24; ++kt) {
        int cur = kt & 1;
        if (kt < 23) stage(cur ^ 1, kt + 1);
        const uint16_t* As = &lds[cur][0];
        const uint16_t* Bs = &lds[cur][4096];
        bf16x8 a[4], bb[4];
        #pragma unroll
        for (int mi = 0; mi < 4; ++mi)
            a[mi] = *(const bf16x8*)(As + (wr * 64 + mi * 16 + l15) * 32 + roff);
        #pragma unroll
        for (int ni = 0; ni < 4; ++ni)
            bb[ni] = *(const bf16x8*)(Bs + (wc * 64 + ni * 16 + l15) * 32 + roff);
        #pragma unroll
        for (int mi = 0; mi < 4; ++mi)
            #pragma unroll
            for (int ni = 0; ni < 4; ++ni)
                acc[mi][ni] = __builtin_amdgcn_mfma_f32_16x16x32_bf16(
                    a[mi], bb[ni], acc[mi][ni], 0, 0, 0);
        __syncthreads();
    }

    float bv[4];
    #pragma unroll
    for (int ni = 0; ni < 4; ++ni) bv[ni] = bias[n0 + wc * 64 + ni * 16 + l15];

    if (MODE == 1 && z == 2) {
        // V^T via LDS transpose. T[col][row] bf16, 128x128 = 32 KB (both bufs),
        // XOR-swizzled; write 8B uint2 (4 rows), read 64-row column runs,
        // store 128B-contiguous per (d, half).
        uint16_t* T = &lds[0][0];
        #pragma unroll
        for (int mi = 0; mi < 4; ++mi) {
            int row = wr * 64 + mi * 16 + lg * 4;
            #pragma unroll
            for (int ni = 0; ni < 4; ++ni) {
                int col = wc * 64 + ni * 16 + l15;
                float v0 = acc[mi][ni][0] + bv[ni], v1 = acc[mi][ni][1] + bv[ni];
                float v2 = acc[mi][ni][2] + bv[ni], v3 = acc[mi][ni][3] + bv[ni];
                int byte = (col << 8) + (row << 1);
                byte ^= (((col & 31) ^ (row >> 6)) << 3);
                *(uint2*)((char*)T + byte) = make_uint2(cvtpk(v0, v1), cvtpk(v2, v3));
            }
        }
        __syncthreads();
        int col = tid >> 1, half = tid & 1;
        int gcol = n0 + col;
        int bb_ = m0 >> 11;                 // tile never crosses batch boundary
        int s = (m0 & 2047) + half * 64;
        uint16_t* dst = Vt + ((size_t)(bb_ * 12 + (gcol >> 6)) * 64 + (gcol & 63)) * 2048 + s;
        uint2 tv[16];
        #pragma unroll
        for (int k = 0; k < 16; ++k) {
            int r = half * 64 + k * 4;
            int byte = (col << 8) + (r << 1);
            byte ^= (((col & 31) ^ (r >> 6)) << 3);
            tv[k] = *(const uint2*)((const char*)T + byte);
        }
        #pragma unroll
        for (int k = 0; k < 8; ++k)
            *(uint4*)(dst + k * 8) = make_uint4(tv[2 * k].x, tv[2 * k].y,
                                                tv[2 * k + 1].x, tv[2 * k + 1].y);
    } else {
        #pragma unroll
        for (int mi = 0; mi < 4; ++mi)
            #pragma unroll
            for (int ni = 0; ni < 4; ++ni)
                #pragma unroll
                for (int r = 0; r < 4; ++r) {
                    int row = m0 + wr * 64 + mi * 16 + lg * 4 + r;
                    int col = n0 + wc * 64 + ni * 16 + l15;
                    float v = acc[mi][ni][r] + bv[ni];
                    if (MODE == 1)
                        ((uint16_t*)Yall + (size_t)z * Y_ELEMS)[(size_t)row * D_MODEL + col] = f2bf(v);
                    else
                        ((float*)Yall)[(size_t)row * D_MODEL + col] = v;
                }
    }
}

// ---------------------------------------------------------------------------
// Chunked causal flash attention, QBLK=128: each wave owns TWO 16-row q-subs
// (rows j*128 + {0,64} + w*16 ..). K-frags hoisted, V-frags shared across subs
// -> 32 MFMA per staged tile at 20 ds_reads (vs 16 MFMA / 16 reads before).
// Grid 960 = 40 units x 24 bh. Writes normalized bf16 partials + t = m+log2(l).
// ---------------------------------------------------------------------------
__global__ __launch_bounds__(256) void attn_mfma(const uint16_t* __restrict__ Q,
                                                 const uint16_t* __restrict__ K,
                                                 const uint16_t* __restrict__ Vt,
                                                 uint16_t* __restrict__ pO1,
                                                 uint16_t* __restrict__ pO2,
                                                 float* __restrict__ tbuf) {
    __shared__ uint16_t ks[2][4096];
    __shared__ uint16_t vs[2][4096];
    __shared__ uint16_t ps[4][2048];   // per-wave, per-sub halves

    const int bx = blockIdx.x;
    const int u = bx / 24, bh = bx % 24;
    const int jc = UNITS[u];
    const int j = jc >> 2, c = jc & 3;
    const int ktlo = c * 8;
    const int nkt = min(8, 2 * j + 2 - ktlo);

    const int b = bh / 12, h = bh % 12;
    const int tid = threadIdx.x, w = tid >> 6, l = tid & 63;
    const int l15 = l & 15, lg = l >> 4;
    const size_t headoff = (size_t)b * SEQ * D_MODEL + h * 64;
    const size_t vhead = ((size_t)(b * 12 + h)) << 17;
    const int sc8 = ((l & 7) ^ ((l >> 3) & 7)) * 8;
    const int srow = w * 16 + (l >> 3);

    // Q B-frags for both subs, pre-scaled by log2(e)/8
    const float QS = 0.125f * 1.44269504088896f;
    bf16x8 qf0[2], qf1[2];
    {
        const uint16_t* qp0 = Q + headoff + (size_t)(j * 128 + w * 16 + l15) * D_MODEL + lg * 8;
        const uint16_t* qp1 = qp0 + (size_t)64 * D_MODEL;
        #pragma unroll
        for (int ds = 0; ds < 2; ++ds) {
            bf16x8 a0 = *(const bf16x8*)(qp0 + ds * 32);
            bf16x8 a1 = *(const bf16x8*)(qp1 + ds * 32);
            #pragma unroll
            for (int jj = 0; jj < 8; ++jj) {
                qf0[ds][jj] = (short)f2bf(bf2f((uint16_t)a0[jj]) * QS);
                qf1[ds][jj] = (short)f2bf(bf2f((uint16_t)a1[jj]) * QS);
            }
        }
    }

    float m0_ = -3e38f, l0_ = 0.f, m1_ = -3e38f, l1_ = 0.f;
    f32x4 oacc0[4], oacc1[4];
    #pragma unroll
    for (int ni = 0; ni < 4; ++ni) {
        oacc0[ni] = (f32x4){0.f, 0.f, 0.f, 0.f};
        oacc1[ni] = (f32x4){0.f, 0.f, 0.f, 0.f};
    }
    const int qg0 = j * 128 + w * 16 + l15;   // sub1: +64

    auto stage = [&](int buf, int kt) {
        const uint16_t* ksrc = K + headoff + (size_t)(kt * 64 + srow) * D_MODEL + sc8;
        glds16(ksrc, &ks[buf][w * 1024]);
        glds16(ksrc + 8 * D_MODEL, &ks[buf][w * 1024 + 512]);
        const uint16_t* vsrc = Vt + vhead + (size_t)srow * SEQ + kt * 64 + sc8;
        glds16(vsrc, &vs[buf][w * 1024]);
        glds16(vsrc + 8 * SEQ, &vs[buf][w * 1024 + 512]);
    };

    stage(0, ktlo);
    for (int it = 0; it < nkt; ++it) {
        const int kt = ktlo + it;
        const int cur = it & 1;
        const bool act0 = (kt <= 2 * j);          // sub0 skips only kt==2j+1
        __syncthreads();
        if (it + 1 < nkt) stage(cur ^ 1, kt + 1);

        // hoisted K frags
        bf16x8 ak[2][4];
        #pragma unroll
        for (int ds = 0; ds < 2; ++ds)
            #pragma unroll
            for (int ki = 0; ki < 4; ++ki) {
                int byte = (ki * 16 + l15) * 128 + ((((ds << 2) + lg) ^ (l15 & 7)) << 4);
                ak[ds][ki] = *(const bf16x8*)((const char*)&ks[cur][0] + byte);
            }
        // S^T for both subs
        f32x4 sacc0[4], sacc1[4];
        #pragma unroll
        for (int ki = 0; ki < 4; ++ki) {
            sacc0[ki] = (f32x4){0.f, 0.f, 0.f, 0.f};
            sacc1[ki] = (f32x4){0.f, 0.f, 0.f, 0.f};
        }
        __builtin_amdgcn_s_setprio(1);
        #pragma unroll
        for (int ds = 0; ds < 2; ++ds)
            #pragma unroll
            for (int ki = 0; ki < 4; ++ki) {
                if (act0)
                    sacc0[ki] = __builtin_amdgcn_mfma_f32_16x16x32_bf16(ak[ds][ki], qf0[ds], sacc0[ki], 0, 0, 0);
                sacc1[ki] = __builtin_amdgcn_mfma_f32_16x16x32_bf16(ak[ds][ki], qf1[ds], sacc1[ki], 0, 0, 0);
            }
        __builtin_amdgcn_s_setprio(0);

        // ---- softmax sub0 ----
        if (act0) {
            const bool diag = (kt == 2 * j);
            float sv[16];
            #pragma unroll
            for (int ki = 0; ki < 4; ++ki)
                #pragma unroll
                for (int r = 0; r < 4; ++r) {
                    float s = sacc0[ki][r];
                    if (diag) {
                        int key = kt * 64 + ki * 16 + lg * 4 + r;
                        if (key > qg0) s = -3e38f;
                    }
                    sv[ki * 4 + r] = s;
                }
            float mx = fmaxf(fmaxf(sv[0], sv[1]), sv[2]);
            #pragma unroll
            for (int i = 3; i < 15; i += 2) mx = fmaxf(fmaxf(mx, sv[i]), sv[i + 1]);
            mx = fmaxf(mx, sv[15]);
            mx = fmaxf(mx, __shfl_xor(mx, 16));
            mx = fmaxf(mx, __shfl_xor(mx, 32));
            if (__any(mx > m0_ + 11.54f)) {
                float mnew = fmaxf(m0_, mx);
                float alpha = __builtin_amdgcn_exp2f(m0_ - mnew);
                l0_ *= alpha;
                float a0 = __shfl(alpha, lg * 4 + 0), a1 = __shfl(alpha, lg * 4 + 1);
                float a2 = __shfl(alpha, lg * 4 + 2), a3 = __shfl(alpha, lg * 4 + 3);
                #pragma unroll
                for (int ni = 0; ni < 4; ++ni) {
                    oacc0[ni][0] *= a0; oacc0[ni][1] *= a1;
                    oacc0[ni][2] *= a2; oacc0[ni][3] *= a3;
                }
                m0_ = mnew;
            }
            float sum = 0.f;
            uint32_t pk[8];
            #pragma unroll
            for (int i = 0; i < 16; i += 2) {
                float p0 = __builtin_amdgcn_exp2f(sv[i] - m0_);
                float p1 = __builtin_amdgcn_exp2f(sv[i + 1] - m0_);
                sum += p0 + p1;
                pk[i >> 1] = cvtpk(p0, p1);
            }
            sum += __shfl_xor(sum, 16);
            sum += __shfl_xor(sum, 32);
            l0_ += sum;
            char* psw = (char*)&ps[w][0];
            #pragma unroll
            for (int ki = 0; ki < 4; ++ki) {
                int byte = (l15 * 128 + ki * 32 + lg * 8) ^ ((l15 & 7) << 4);
                *(uint2*)(psw + byte) = make_uint2(pk[ki * 2], pk[ki * 2 + 1]);
            }
        }
        // ---- softmax sub1 ----
        {
            const bool diag = (kt == 2 * j + 1);
            float sv[16];
            #pragma unroll
            for (int ki = 0; ki < 4; ++ki)
                #pragma unroll
                for (int r = 0; r < 4; ++r) {
                    float s = sacc1[ki][r];
                    if (diag) {
                        int key = kt * 64 + ki * 16 + lg * 4 + r;
                        if (key > qg0 + 64) s = -3e38f;
                    }
                    sv[ki * 4 + r] = s;
                }
            float mx = fmaxf(fmaxf(sv[0], sv[1]), sv[2]);
            #pragma unroll
            for (int i = 3; i < 15; i += 2) mx = fmaxf(fmaxf(mx, sv[i]), sv[i + 1]);
            mx = fmaxf(mx, sv[15]);
            mx = fmaxf(mx, __shfl_xor(mx, 16));
            mx = fmaxf(mx, __shfl_xor(mx, 32));
            if (__any(mx > m1_ + 11.54f)) {
                float mnew = fmaxf(m1_, mx);
                float alpha = __builtin_amdgcn_exp2f(m1_ - mnew);
                l1_ *= alpha;
                float a0 = __shfl(alpha, lg * 4 + 0), a1 = __shfl(alpha, lg * 4 + 1);
                float a2 = __shfl(alpha, lg * 4 + 2), a3 = __shfl(alpha, lg * 4 + 3);
                #pragma unroll
                for (int ni = 0; ni < 4; ++ni) {
                    oacc1[ni][0] *= a0; oacc1[ni][1] *= a1;
                    oacc1[ni][2] *= a2; oacc1[ni][3] *= a3;
                }
                m1_ = mnew;
            }
            float sum = 0.f;
            uint32_t pk[8];
            #pragma unroll
            for (int i = 0; i < 16; i += 2) {
                float p0 = __builtin_amdgcn_exp2f(sv[i] - m1_);
                float p1 = __builtin_amdgcn_exp2f(sv[i + 1] - m1_);
                sum += p0 + p1;
                pk[i >> 1] = cvtpk(p0, p1);
            }
            sum += __shfl_xor(sum, 16);
            sum += __shfl_xor(sum, 32);
            l1_ += sum;
            char* psw = (char*)&ps[w][1024];
            #pragma unroll
            for (int ki = 0; ki < 4; ++ki) {
                int byte = (l15 * 128 + ki * 32 + lg * 8) ^ ((l15 & 7) << 4);
                *(uint2*)(psw + byte) = make_uint2(pk[ki * 2], pk[ki * 2 + 1]);
            }
        }
        asm volatile("s_waitcnt lgkmcnt(0)" ::: "memory");
        __builtin_amdgcn_sched_barrier(0);

        // ---- PV: shared V frags, both subs ----
        __builtin_amdgcn_s_setprio(1);
        #pragma unroll
        for (int kss = 0; kss < 2; ++kss) {
            int pbyte = l15 * 128 + ((((kss << 2) + lg) ^ (l15 & 7)) << 4);
            bf16x8 ap0 = *(const bf16x8*)((const char*)&ps[w][0] + pbyte);
            bf16x8 ap1 = *(const bf16x8*)((const char*)&ps[w][1024] + pbyte);
            #pragma unroll
            for (int ni = 0; ni < 4; ++ni) {
                int vbyte = (ni * 16 + l15) * 128 + ((((kss << 2) + lg) ^ (l15 & 7)) << 4);
                bf16x8 bvv = *(const bf16x8*)((const char*)&vs[cur][0] + vbyte);
                if (act0)
                    oacc0[ni] = __builtin_amdgcn_mfma_f32_16x16x32_bf16(ap0, bvv, oacc0[ni], 0, 0, 0);
                oacc1[ni] = __builtin_amdgcn_mfma_f32_16x16x32_bf16(ap1, bvv, oacc1[ni], 0, 0, 0);
            }
        }
        __builtin_amdgcn_s_setprio(0);
    }

    // Epilogue: normalized bf16 partials (128 q x 64 d per unit) + weights
    uint16_t* op = (bx < 768) ? (pO1 + (size_t)bx * 8192)
                              : (pO2 + (size_t)(bx - 768) * 8192);
    {
        float li0 = 1.f / __shfl(l0_, lg * 4 + 0), li1 = 1.f / __shfl(l0_, lg * 4 + 1);
        float li2 = 1.f / __shfl(l0_, lg * 4 + 2), li3 = 1.f / __shfl(l0_, lg * 4 + 3);
        #pragma unroll
        for (int ni = 0; ni < 4; ++ni) {
            int rbase = (w * 16 + lg * 4) * 64 + ni * 16 + l15;
            op[rbase + 0 * 64] = f2bf(oacc0[ni][0] * li0);
            op[rbase + 1 * 64] = f2bf(oacc0[ni][1] * li1);
            op[rbase + 2 * 64] = f2bf(oacc0[ni][2] * li2);
            op[rbase + 3 * 64] = f2bf(oacc0[ni][3] * li3);
        }
    }
    {
        float li0 = 1.f / __shfl(l1_, lg * 4 + 0), li1 = 1.f / __shfl(l1_, lg * 4 + 1);
        float li2 = 1.f / __shfl(l1_, lg * 4 + 2), li3 = 1.f / __shfl(l1_, lg * 4 + 3);
        #pragma unroll
        for (int ni = 0; ni < 4; ++ni) {
            int rbase = (64 + w * 16 + lg * 4) * 64 + ni * 16 + l15;
            op[rbase + 0 * 64] = f2bf(oacc1[ni][0] * li0);
            op[rbase + 1 * 64] = f2bf(oacc1[ni][1] * li1);
            op[rbase + 2 * 64] = f2bf(oacc1[ni][2] * li2);
            op[rbase + 3 * 64] = f2bf(oacc1[ni][3] * li3);
        }
    }
    if (lg == 0) {
        tbuf[(size_t)bx * 128 + w * 16 + l15] = m0_ + __log2f(l0_);
        tbuf[(size_t)bx * 128 + 64 + w * 16 + l15] = m1_ + __log2f(l1_);
    }
}

// ---------------------------------------------------------------------------
// Combine partials per (bh, j): O = sum_c 2^(t_c - tmax) * Ohat_c / denom.
// Grid 384 blocks (24 bh x 16 j); thread -> (q = tid/2, d0 = (tid&1)*32).
// ---------------------------------------------------------------------------
__global__ __launch_bounds__(256) void attn_combine(const uint16_t* __restrict__ pO1,
                                                    const uint16_t* __restrict__ pO2,
                                                    const float* __restrict__ tbuf,
                                                    uint16_t* __restrict__ Obf) {
    __shared__ float t_lds[4][128];
    const int bx = blockIdx.x;
    const int j = bx & 15, bh = bx >> 4;
    const int b = bh / 12, h = bh % 12;
    const int nc = (j < 4) ? 1 : (j < 8) ? 2 : (j < 12) ? 3 : 4;
    const int tid = threadIdx.x;
    for (int e = tid; e < nc * 128; e += 256) {
        int cc = e >> 7, q = e & 127;
        int ug = UBASE[j * 4 + cc] * 24 + bh;
        t_lds[cc][q] = tbuf[(size_t)ug * 128 + q];
    }
    __syncthreads();

    const int q = tid >> 1, d0 = (tid & 1) * 32;
    float tmax = t_lds[0][q];
    for (int c = 1; c < nc; ++c) tmax = fmaxf(tmax, t_lds[c][q]);
    float acc[32];
    #pragma unroll
    for (int jj = 0; jj < 32; ++jj) acc[jj] = 0.f;
    float denom = 0.f;
    for (int c = 0; c < nc; ++c) {
        float wgt = __builtin_amdgcn_exp2f(t_lds[c][q] - tmax);
        denom += wgt;
        int ug = UBASE[j * 4 + c] * 24 + bh;
        const uint16_t* op = (ug < 768) ? (pO1 + (size_t)ug * 8192)
                                        : (pO2 + (size_t)(ug - 768) * 8192);
        #pragma unroll
        for (int v = 0; v < 4; ++v) {
            bf16x8 vv = *(const bf16x8*)(op + q * 64 + d0 + v * 8);
            #pragma unroll
            for (int jj = 0; jj < 8; ++jj)
                acc[v * 8 + jj] += bf2f((uint16_t)vv[jj]) * wgt;
        }
    }
    float inv = 1.f / denom;
    uint32_t outp[16];
    #pragma unroll
    for (int jj = 0; jj < 16; ++jj)
        outp[jj] = cvtpk(acc[2 * jj] * inv, acc[2 * jj + 1] * inv);
    size_t rb = (size_t)(b * SEQ + j * 128 + q) * D_MODEL + h * 64 + d0;
    *(uint4*)(Obf + rb)      = make_uint4(outp[0], outp[1], outp[2], outp[3]);
    *(uint4*)(Obf + rb + 8)  = make_uint4(outp[4], outp[5], outp[6], outp[7]);
    *(uint4*)(Obf + rb + 16) = make_uint4(outp[8], outp[9], outp[10], outp[11]);
    *(uint4*)(Obf + rb + 24) = make_uint4(outp[12], outp[13], outp[14], outp[15]);
}

// ---------------------------------------------------------------------------
// Workspace (bytes):
//   wsA @ 0 (262144) | wsB @ 262144 (4718592)       [dead after buildC]
//   Wbf @ 4980736 (4718592) bf16 [4][out][in]
//   xbf @ 9699328 (6291456) [dead after gemm<1>] -> partial units 768..959
//   tbuf @ 12845056 (491520 = 960*128*4)
//   Qbf @ 15990784 | Kbf @ 22282240 | Vtbf @ 28573696 | Obf @ 34865152
//   d_out (12582912 B) = partial units 0..767 (768 x 16KB, exact fit)
// ---------------------------------------------------------------------------
extern "C" void kernel_launch(void* const* d_in, const int* in_sizes, int n_in,
                              void* d_out, int out_size, void* d_ws, size_t ws_size,
                              hipStream_t stream) {
    const float* x = (const float*)d_in[0];
    TTPtrs P;
    const float* biases[4];
    const int base[4] = {2, 7, 12, 17};  // q, k, v, o parameter groups
    for (int t = 0; t < 4; t++) {
        P.c0[t] = (const float*)d_in[base[t] + 0];
        P.c1[t] = (const float*)d_in[base[t] + 1];
        P.c2[t] = (const float*)d_in[base[t] + 2];
        P.c3[t] = (const float*)d_in[base[t] + 3];
        biases[t] = (const float*)d_in[base[t] + 4];
    }

    char* ws = (char*)d_ws;
    float* wsA = (float*)(ws + 0);
    float* wsB = (float*)(ws + 262144);
    uint16_t* Wbf = (uint16_t*)(ws + 4980736);
    uint16_t* xbf = (uint16_t*)(ws + 9699328);
    uint16_t* pO2 = (uint16_t*)(ws + 9699328);     // overlaps xbf (dead by attn)
    float* tbuf = (float*)(ws + 12845056);
    uint16_t* Qbf = (uint16_t*)(ws + 15990784);
    uint16_t* Kbf = (uint16_t*)(ws + 22282240);
    uint16_t* Vtbf = (uint16_t*)(ws + 28573696);
    uint16_t* Obf = (uint16_t*)(ws + 34865152);
    uint16_t* pO1 = (uint16_t*)d_out;              // d_out scratch (rewritten by o-proj)
    (void)Kbf;

    pre_kernel<<<dim3(256 + 3072), 256, 0, stream>>>(P, wsA, x, xbf);
    tt_buildB<<<dim3(1152, 4), 256, 0, stream>>>(P, wsA, wsB);
    tt_buildC<<<dim3(256, 4), 256, 0, stream>>>(P, wsB, Wbf);

    // q, k projections (bf16, row-major); v written transposed to Vtbf
    gemm_mfma<1><<<dim3(32, 6, 3), 256, 0, stream>>>(xbf, Wbf, biases[0], biases[1],
                                                     biases[2], (void*)Qbf, Vtbf);
    // chunked causal attention (QBLK=128) -> partials, then combine -> Obf
    attn_mfma<<<dim3(960), 256, 0, stream>>>(Qbf, Kbf, Vtbf, pO1, pO2, tbuf);
    attn_combine<<<dim3(384), 256, 0, stream>>>(pO1, pO2, tbuf, Obf);

    // output projection (fp32 out -> d_out)
    gemm_mfma<0><<<dim3(32, 6, 1), 256, 0, stream>>>(Obf, Wbf + 3 * (size_t)W_ELEMS,
                                                     biases[3], biases[3], biases[3],
                                                     d_out, nullptr);
}

// Round 10
// 237.766 us; speedup vs baseline: 1.0983x; 1.0983x over previous
//
#include <hip/hip_runtime.h>
#include <cstddef>
#include <cstdint>

// Problem constants
#define D_MODEL 768
#define N_HEADS 12
#define SEQ 2048
#define BATCH 2
#define NROWS (BATCH * SEQ)          // 4096
#define W_ELEMS (D_MODEL * D_MODEL)  // 589824
#define Y_ELEMS (NROWS * D_MODEL)    // 3145728

typedef __attribute__((ext_vector_type(8))) short bf16x8;
typedef __attribute__((ext_vector_type(4))) float f32x4;

struct TTPtrs {
    const float* c0[4];
    const float* c1[4];
    const float* c2[4];
    const float* c3[4];
};

__device__ __forceinline__ float bf2f(uint16_t u) {
    union { uint32_t u; float f; } c; c.u = ((uint32_t)u) << 16; return c.f;
}
__device__ __forceinline__ uint16_t f2bf(float f) {
    union { float f; uint32_t u; } c; c.f = f;
    uint32_t x = c.u + 0x7fffu + ((c.u >> 16) & 1u);   // RNE
    return (uint16_t)(x >> 16);
}
__device__ __forceinline__ uint32_t cvtpk(float lo, float hi) {
    uint32_t r;
    asm("v_cvt_pk_bf16_f32 %0, %1, %2" : "=v"(r) : "v"(lo), "v"(hi));
    return r;
}
__device__ __forceinline__ void glds16(const void* g, void* l) {
    auto gp = reinterpret_cast<const __attribute__((address_space(1))) uint32_t*>(
        reinterpret_cast<uintptr_t>(g));
    auto lp = reinterpret_cast<__attribute__((address_space(3))) uint32_t*>(
        reinterpret_cast<uintptr_t>(l));
    __builtin_amdgcn_global_load_lds(gp, lp, 16, 0, 0);
}

// ---------------------------------------------------------------------------
// pre_kernel: fused buildA (256 blocks) and x -> bf16 conversion (3072 blocks).
// ---------------------------------------------------------------------------
__global__ __launch_bounds__(256) void pre_kernel(TTPtrs P, float* __restrict__ wsA,
                                                  const float* __restrict__ x,
                                                  uint16_t* __restrict__ xb) {
    const int bx = blockIdx.x;
    if (bx < 256) {
        const int mat = bx >> 6;
        const float* c0 = P.c0[mat];
        const float* c1 = P.c1[mat];
        float* A = wsA + mat * 16384;
        int idx = (bx & 63) * 256 + threadIdx.x;
        int s = idx & 63, pj = (idx >> 6) & 15, mi = idx >> 10;
        float acc = 0.f;
        #pragma unroll 8
        for (int r = 0; r < 32; r++)
            acc = fmaf(c0[mi * 32 + r], c1[(r * 16 + pj) * 64 + s], acc);
        A[idx] = acc;
    } else {
        int idx = ((bx - 256) * 256 + threadIdx.x) * 4;
        float4 v = *(const float4*)(x + idx);
        *(uint2*)(xb + idx) = make_uint2(cvtpk(v.x, v.y), cvtpk(v.z, v.w));
    }
}

// Stage B: B[mi][pj][qk][t] = sum_s A * c2, 16*16*36*32 per matrix
__global__ __launch_bounds__(256) void tt_buildB(TTPtrs P, const float* __restrict__ wsA,
                                                 float* __restrict__ wsB) {
    const int mat = blockIdx.y;
    const float* c2 = P.c2[mat];
    const float* A = wsA + mat * 16384;
    float* B = wsB + (size_t)mat * 294912;
    int idx = blockIdx.x * 256 + threadIdx.x;
    int t = idx & 31;
    int rest = idx >> 5;
    int qk = rest % 36;
    int rest2 = rest / 36;
    int pj = rest2 & 15, mi = rest2 >> 4;
    const float* Arow = A + (mi * 16 + pj) * 64;
    float acc = 0.f;
    #pragma unroll 8
    for (int s = 0; s < 64; s++)
        acc = fmaf(Arow[s], c2[(s * 36 + qk) * 32 + t], acc);
    B[idx] = acc;
}

// Stage C: LDS-staged; block = one (mat, mi, pj); 9 outputs/thread.
__global__ __launch_bounds__(256) void tt_buildC(TTPtrs P, const float* __restrict__ wsB,
                                                 uint16_t* __restrict__ Wbf) {
    __shared__ float b_lds[36 * 33];
    __shared__ float c_lds[32 * 64];
    const int mat = blockIdx.y;
    const int mipj = blockIdx.x;
    const int mi = mipj >> 4, pj = mipj & 15;
    const int m = mi >> 2, i = mi & 3, p = pj >> 2, j = pj & 3;
    const float* Bsrc = wsB + (size_t)mat * 294912 + (size_t)mipj * 1152;
    const float* c3 = P.c3[mat];
    uint16_t* Wt = Wbf + (size_t)mat * W_ELEMS;
    const int tid = threadIdx.x;

    for (int e = tid; e < 1152; e += 256) {
        int qk = e >> 5, t = e & 31;
        b_lds[qk * 33 + t] = Bsrc[e];
    }
    for (int e = tid; e < 2048; e += 256)
        c_lds[e] = c3[e];
    __syncthreads();

    const int outbase = (m * 4 + p) * 48;
    const int inbase = (i * 4 + j) * 48;
    #pragma unroll
    for (int n = 0; n < 9; n++) {
        int idx = n * 256 + tid;
        int qu = idx / 48, kl = idx % 48;
        int q = qu >> 3, u = qu & 7, k = kl >> 3, l = kl & 7;
        const float* brow = &b_lds[(q * 6 + k) * 33];
        const float* crow = &c_lds[u * 8 + l];
        float acc = 0.f;
        #pragma unroll 8
        for (int t = 0; t < 32; t++)
            acc = fmaf(brow[t], crow[t * 64], acc);
        Wt[(size_t)(outbase + qu) * D_MODEL + inbase + kl] = f2bf(acc);
    }
}

// ---------------------------------------------------------------------------
// bf16 MFMA GEMM. MODE 0: f32 out. MODE 1: bf16 out; z==2 writes V transposed
// to Vt[b][h][d][s] via LDS-transpose (coalesced 128B runs; measured ~-19us
// vs the old 8B-at-4KB-stride scatter).
// ---------------------------------------------------------------------------
template <int MODE>
__global__ __launch_bounds__(256) void gemm_mfma(const uint16_t* __restrict__ X,
                                                 const uint16_t* __restrict__ Wall,
                                                 const float* __restrict__ b0,
                                                 const float* __restrict__ b1,
                                                 const float* __restrict__ b2,
                                                 void* __restrict__ Yall,
                                                 uint16_t* __restrict__ Vt) {
    __shared__ uint16_t lds[2][8192];
    const int z = blockIdx.z;
    const uint16_t* W = Wall + (size_t)z * W_ELEMS;
    const float* bias = (z == 0) ? b0 : (z == 1 ? b1 : b2);
    const int m0 = blockIdx.x * 128, n0 = blockIdx.y * 128;
    const int tid = threadIdx.x, w = tid >> 6, l = tid & 63;
    const int wr = w >> 1, wc = w & 1;
    const int l15 = l & 15, lg = l >> 4;

    const int srow = w * 32 + (l >> 2);
    const int scol = ((l & 3) ^ ((l >> 2) & 3)) * 8;
    const uint16_t* Abase = X + (size_t)(m0 + srow) * D_MODEL + scol;
    const uint16_t* Bbase = W + (size_t)(n0 + srow) * D_MODEL + scol;

    f32x4 acc[4][4];
    #pragma unroll
    for (int mi = 0; mi < 4; ++mi)
        #pragma unroll
        for (int ni = 0; ni < 4; ++ni) acc[mi][ni] = (f32x4){0.f, 0.f, 0.f, 0.f};

    auto stage = [&](int buf, int kt) {
        const uint16_t* A0 = Abase + kt * 32;
        const uint16_t* B0 = Bbase + kt * 32;
        glds16(A0, &lds[buf][w * 1024]);
        glds16(A0 + 16 * D_MODEL, &lds[buf][w * 1024 + 512]);
        glds16(B0, &lds[buf][4096 + w * 1024]);
        glds16(B0 + 16 * D_MODEL, &lds[buf][4096 + w * 1024 + 512]);
    };

    stage(0, 0);
    __syncthreads();
    const int roff = ((lg ^ (l & 3)) << 3);
    for (int kt = 0; kt < 24; ++kt) {
        int cur = kt & 1;
        if (kt < 23) stage(cur ^ 1, kt + 1);
        const uint16_t* As = &lds[cur][0];
        const uint16_t* Bs = &lds[cur][4096];
        bf16x8 a[4], bb[4];
        #pragma unroll
        for (int mi = 0; mi < 4; ++mi)
            a[mi] = *(const bf16x8*)(As + (wr * 64 + mi * 16 + l15) * 32 + roff);
        #pragma unroll
        for (int ni = 0; ni < 4; ++ni)
            bb[ni] = *(const bf16x8*)(Bs + (wc * 64 + ni * 16 + l15) * 32 + roff);
        #pragma unroll
        for (int mi = 0; mi < 4; ++mi)
            #pragma unroll
            for (int ni = 0; ni < 4; ++ni)
                acc[mi][ni] = __builtin_amdgcn_mfma_f32_16x16x32_bf16(
                    a[mi], bb[ni], acc[mi][ni], 0, 0, 0);
        __syncthreads();
    }

    float bv[4];
    #pragma unroll
    for (int ni = 0; ni < 4; ++ni) bv[ni] = bias[n0 + wc * 64 + ni * 16 + l15];

    if (MODE == 1 && z == 2) {
        // V^T via LDS transpose. T[col][row] bf16, 128x128 = 32 KB (both bufs),
        // XOR-swizzled; write 8B uint2 (4 rows), read column runs,
        // store 128B-contiguous per (d, half).
        uint16_t* T = &lds[0][0];
        #pragma unroll
        for (int mi = 0; mi < 4; ++mi) {
            int row = wr * 64 + mi * 16 + lg * 4;
            #pragma unroll
            for (int ni = 0; ni < 4; ++ni) {
                int col = wc * 64 + ni * 16 + l15;
                float v0 = acc[mi][ni][0] + bv[ni], v1 = acc[mi][ni][1] + bv[ni];
                float v2 = acc[mi][ni][2] + bv[ni], v3 = acc[mi][ni][3] + bv[ni];
                int byte = (col << 8) + (row << 1);
                byte ^= (((col & 31) ^ (row >> 6)) << 3);
                *(uint2*)((char*)T + byte) = make_uint2(cvtpk(v0, v1), cvtpk(v2, v3));
            }
        }
        __syncthreads();
        int col = tid >> 1, half = tid & 1;
        int gcol = n0 + col;
        int bb_ = m0 >> 11;                 // tile never crosses batch boundary
        int s = (m0 & 2047) + half * 64;
        uint16_t* dst = Vt + ((size_t)(bb_ * 12 + (gcol >> 6)) * 64 + (gcol & 63)) * 2048 + s;
        uint2 tv[16];
        #pragma unroll
        for (int k = 0; k < 16; ++k) {
            int r = half * 64 + k * 4;
            int byte = (col << 8) + (r << 1);
            byte ^= (((col & 31) ^ (r >> 6)) << 3);
            tv[k] = *(const uint2*)((const char*)T + byte);
        }
        #pragma unroll
        for (int k = 0; k < 8; ++k)
            *(uint4*)(dst + k * 8) = make_uint4(tv[2 * k].x, tv[2 * k].y,
                                                tv[2 * k + 1].x, tv[2 * k + 1].y);
    } else {
        #pragma unroll
        for (int mi = 0; mi < 4; ++mi)
            #pragma unroll
            for (int ni = 0; ni < 4; ++ni)
                #pragma unroll
                for (int r = 0; r < 4; ++r) {
                    int row = m0 + wr * 64 + mi * 16 + lg * 4 + r;
                    int col = n0 + wc * 64 + ni * 16 + l15;
                    float v = acc[mi][ni][r] + bv[ni];
                    if (MODE == 1)
                        ((uint16_t*)Yall + (size_t)z * Y_ELEMS)[(size_t)row * D_MODEL + col] = f2bf(v);
                    else
                        ((float*)Yall)[(size_t)row * D_MODEL + col] = v;
                }
    }
}

// ---------------------------------------------------------------------------
// Chunked causal flash attention, QBLK=64 (52-VGPR version; QBLK=128 regressed:
// 116 VGPR, MfmaUtil 6.5%, +43us). Key-split for load balance: chunk = up to
// 8 key-tiles of one (bh, qt); 80 units/bh, big chunks first; grid 1920.
// Writes NORMALIZED partial O (bf16) + per-q combine weight t = m + log2(l).
// ---------------------------------------------------------------------------
__global__ __launch_bounds__(256) void attn_mfma(const uint16_t* __restrict__ Q,
                                                 const uint16_t* __restrict__ K,
                                                 const uint16_t* __restrict__ Vt,
                                                 uint16_t* __restrict__ pO1,
                                                 uint16_t* __restrict__ pO2,
                                                 float* __restrict__ tbuf) {
    __shared__ uint16_t ks[2][4096];
    __shared__ uint16_t vs[2][4096];
    __shared__ uint16_t ps[4][1024];

    const int bx = blockIdx.x;
    const int u = bx / 24;
    const int bh = bx % 24;
    int g, c;
    if (u < 32)      { g = u >> 2,            c = u & 3; }
    else if (u < 56) { int t = u - 32; g = 8 + t / 3,  c = t % 3; }
    else if (u < 72) { int t = u - 56; g = 16 + (t >> 1), c = t & 1; }
    else             { g = 24 + (u - 72),     c = 0; }
    const int qt = 31 - g;
    const int ktlo = c * 8;
    const int kthi = min(ktlo + 7, qt);
    const int nkt = kthi - ktlo + 1;

    const int b = bh / 12, h = bh % 12;
    const int tid = threadIdx.x, w = tid >> 6, l = tid & 63;
    const int l15 = l & 15, lg = l >> 4;
    const size_t headoff = (size_t)b * SEQ * D_MODEL + h * 64;
    const size_t vhead = ((size_t)(b * 12 + h)) << 17;
    const int sc8 = ((l & 7) ^ ((l >> 3) & 7)) * 8;
    const int srow = w * 16 + (l >> 3);

    // Q B-frags, pre-scaled by log2(e)/8 (exp2-domain scores)
    const float QS = 0.125f * 1.44269504088896f;
    bf16x8 qf[2];
    {
        const uint16_t* qp = Q + headoff + (size_t)(qt * 64 + w * 16 + l15) * D_MODEL + lg * 8;
        #pragma unroll
        for (int ds = 0; ds < 2; ++ds) {
            bf16x8 qv = *(const bf16x8*)(qp + ds * 32);
            #pragma unroll
            for (int j = 0; j < 8; ++j)
                qf[ds][j] = (short)f2bf(bf2f((uint16_t)qv[j]) * QS);
        }
    }

    float m_ = -3e38f, l_ = 0.f;
    f32x4 oacc[4];
    #pragma unroll
    for (int ni = 0; ni < 4; ++ni) oacc[ni] = (f32x4){0.f, 0.f, 0.f, 0.f};
    const int qglob = qt * 64 + w * 16 + l15;

    auto stage = [&](int buf, int kt) {
        const uint16_t* ksrc = K + headoff + (size_t)(kt * 64 + srow) * D_MODEL + sc8;
        glds16(ksrc, &ks[buf][w * 1024]);
        glds16(ksrc + 8 * D_MODEL, &ks[buf][w * 1024 + 512]);
        const uint16_t* vsrc = Vt + vhead + (size_t)srow * SEQ + kt * 64 + sc8;
        glds16(vsrc, &vs[buf][w * 1024]);
        glds16(vsrc + 8 * SEQ, &vs[buf][w * 1024 + 512]);
    };

    stage(0, ktlo);
    for (int it = 0; it < nkt; ++it) {
        const int kt = ktlo + it;
        const int cur = it & 1;
        __syncthreads();
        if (it + 1 < nkt) stage(cur ^ 1, kt + 1);

        // S^T[key][q] = K · Qs^T
        f32x4 sacc[4];
        #pragma unroll
        for (int ki = 0; ki < 4; ++ki) sacc[ki] = (f32x4){0.f, 0.f, 0.f, 0.f};
        __builtin_amdgcn_s_setprio(1);
        #pragma unroll
        for (int ds = 0; ds < 2; ++ds)
            #pragma unroll
            for (int ki = 0; ki < 4; ++ki) {
                int byte = (ki * 16 + l15) * 128 + ((((ds << 2) + lg) ^ (l15 & 7)) << 4);
                bf16x8 ak = *(const bf16x8*)((const char*)&ks[cur][0] + byte);
                sacc[ki] = __builtin_amdgcn_mfma_f32_16x16x32_bf16(ak, qf[ds], sacc[ki], 0, 0, 0);
            }
        __builtin_amdgcn_s_setprio(0);

        const bool diag = (kt == qt);
        float sv[16];
        #pragma unroll
        for (int ki = 0; ki < 4; ++ki)
            #pragma unroll
            for (int r = 0; r < 4; ++r) {
                float s = sacc[ki][r];
                if (diag) {
                    int key = kt * 64 + ki * 16 + lg * 4 + r;
                    if (key > qglob) s = -3e38f;
                }
                sv[ki * 4 + r] = s;
            }
        // max tree (max3-fusable)
        float mx = fmaxf(fmaxf(sv[0], sv[1]), sv[2]);
        #pragma unroll
        for (int i = 3; i < 15; i += 2) mx = fmaxf(fmaxf(mx, sv[i]), sv[i + 1]);
        mx = fmaxf(mx, sv[15]);
        mx = fmaxf(mx, __shfl_xor(mx, 16));
        mx = fmaxf(mx, __shfl_xor(mx, 32));
        if (__any(mx > m_ + 11.54f)) {         // defer-max (T13), log2 units
            float mnew = fmaxf(m_, mx);
            float alpha = __builtin_amdgcn_exp2f(m_ - mnew);
            l_ *= alpha;
            float a0 = __shfl(alpha, lg * 4 + 0), a1 = __shfl(alpha, lg * 4 + 1);
            float a2 = __shfl(alpha, lg * 4 + 2), a3 = __shfl(alpha, lg * 4 + 3);
            #pragma unroll
            for (int ni = 0; ni < 4; ++ni) {
                oacc[ni][0] *= a0; oacc[ni][1] *= a1;
                oacc[ni][2] *= a2; oacc[ni][3] *= a3;
            }
            m_ = mnew;
        }
        float sum = 0.f;
        uint32_t pk[8];
        #pragma unroll
        for (int i = 0; i < 16; i += 2) {
            float p0 = __builtin_amdgcn_exp2f(sv[i] - m_);
            float p1 = __builtin_amdgcn_exp2f(sv[i + 1] - m_);
            sum += p0 + p1;
            pk[i >> 1] = cvtpk(p0, p1);
        }
        sum += __shfl_xor(sum, 16);
        sum += __shfl_xor(sum, 32);
        l_ += sum;

        uint16_t* psw = &ps[w][0];
        #pragma unroll
        for (int ki = 0; ki < 4; ++ki) {
            int byte = (l15 * 128 + ki * 32 + lg * 8) ^ ((l15 & 7) << 4);
            *(uint2*)((char*)psw + byte) = make_uint2(pk[ki * 2], pk[ki * 2 + 1]);
        }
        asm volatile("s_waitcnt lgkmcnt(0)" ::: "memory");
        __builtin_amdgcn_sched_barrier(0);

        __builtin_amdgcn_s_setprio(1);
        #pragma unroll
        for (int kss = 0; kss < 2; ++kss) {
            int pbyte = l15 * 128 + ((((kss << 2) + lg) ^ (l15 & 7)) << 4);
            bf16x8 ap = *(const bf16x8*)((const char*)psw + pbyte);
            #pragma unroll
            for (int ni = 0; ni < 4; ++ni) {
                int vbyte = (ni * 16 + l15) * 128 + ((((kss << 2) + lg) ^ (l15 & 7)) << 4);
                bf16x8 bv = *(const bf16x8*)((const char*)&vs[cur][0] + vbyte);
                oacc[ni] = __builtin_amdgcn_mfma_f32_16x16x32_bf16(ap, bv, oacc[ni], 0, 0, 0);
            }
        }
        __builtin_amdgcn_s_setprio(0);
    }

    // Epilogue: normalized partial O (bf16) + combine weight t = m + log2(l)
    float li0 = 1.f / __shfl(l_, lg * 4 + 0), li1 = 1.f / __shfl(l_, lg * 4 + 1);
    float li2 = 1.f / __shfl(l_, lg * 4 + 2), li3 = 1.f / __shfl(l_, lg * 4 + 3);
    uint16_t* op = (bx < 1536) ? (pO1 + (size_t)bx * 4096)
                               : (pO2 + (size_t)(bx - 1536) * 4096);
    #pragma unroll
    for (int ni = 0; ni < 4; ++ni) {
        int col = ni * 16 + l15;
        int rbase = (w * 16 + lg * 4) * 64 + col;
        op[rbase + 0 * 64] = f2bf(oacc[ni][0] * li0);
        op[rbase + 1 * 64] = f2bf(oacc[ni][1] * li1);
        op[rbase + 2 * 64] = f2bf(oacc[ni][2] * li2);
        op[rbase + 3 * 64] = f2bf(oacc[ni][3] * li3);
    }
    if (lg == 0)
        tbuf[(size_t)bx * 64 + w * 16 + l15] = m_ + __log2f(l_);
}

// ---------------------------------------------------------------------------
// Combine partial chunks per (bh, qt): O = sum_c 2^(t_c - tmax) * Ohat_c / denom.
// Grid 768 blocks; thread -> (q = tid/4, d-range = (tid&3)*16 .. +15).
// ---------------------------------------------------------------------------
__global__ __launch_bounds__(256) void attn_combine(const uint16_t* __restrict__ pO1,
                                                    const uint16_t* __restrict__ pO2,
                                                    const float* __restrict__ tbuf,
                                                    uint16_t* __restrict__ Obf) {
    __shared__ float t_lds[4][64];
    const int bx = blockIdx.x;
    const int qt = bx & 31, bh = bx >> 5;
    const int b = bh / 12, h = bh % 12;
    const int g = 31 - qt;
    const int u_base = (g < 8) ? 4 * g : (g < 16) ? 32 + 3 * (g - 8)
                     : (g < 24) ? 56 + 2 * (g - 16) : 72 + (g - 24);
    const int nc = (g < 8) ? 4 : (g < 16) ? 3 : (g < 24) ? 2 : 1;
    const int tid = threadIdx.x;
    if (tid < nc * 64) {
        int c = tid >> 6, q = tid & 63;
        t_lds[c][q] = tbuf[(size_t)((u_base + c) * 24 + bh) * 64 + q];
    }
    __syncthreads();

    const int q = tid >> 2, d0 = (tid & 3) * 16;
    float tmax = t_lds[0][q];
    for (int c = 1; c < nc; ++c) tmax = fmaxf(tmax, t_lds[c][q]);
    float acc[16];
    #pragma unroll
    for (int j = 0; j < 16; ++j) acc[j] = 0.f;
    float denom = 0.f;
    for (int c = 0; c < nc; ++c) {
        float wgt = __builtin_amdgcn_exp2f(t_lds[c][q] - tmax);
        denom += wgt;
        int ug = (u_base + c) * 24 + bh;
        const uint16_t* op = (ug < 1536) ? (pO1 + (size_t)ug * 4096)
                                         : (pO2 + (size_t)(ug - 1536) * 4096);
        bf16x8 v0 = *(const bf16x8*)(op + q * 64 + d0);
        bf16x8 v1 = *(const bf16x8*)(op + q * 64 + d0 + 8);
        #pragma unroll
        for (int j = 0; j < 8; ++j) {
            acc[j]     += bf2f((uint16_t)v0[j]) * wgt;
            acc[8 + j] += bf2f((uint16_t)v1[j]) * wgt;
        }
    }
    float inv = 1.f / denom;
    uint32_t outp[8];
    #pragma unroll
    for (int j = 0; j < 8; ++j)
        outp[j] = cvtpk(acc[2 * j] * inv, acc[2 * j + 1] * inv);
    size_t rb = (size_t)(b * SEQ + qt * 64 + q) * D_MODEL + h * 64 + d0;
    *(uint4*)(Obf + rb)     = make_uint4(outp[0], outp[1], outp[2], outp[3]);
    *(uint4*)(Obf + rb + 8) = make_uint4(outp[4], outp[5], outp[6], outp[7]);
}

// ---------------------------------------------------------------------------
// Workspace (bytes):
//   wsA @ 0 (262144) | wsB @ 262144 (4718592)       [dead after buildC]
//   Wbf @ 4980736 (4718592) bf16 [4][out][in]
//   xbf @ 9699328 (6291456) [dead after gemm<1>] -> partial units 1536..1919
//   tbuf @ 12845056 (491520)
//   Qbf @ 15990784 | Kbf @ 22282240 | Vtbf @ 28573696 | Obf @ 34865152
//   d_out (12582912 B) = partial units 0..1535 (fully overwritten by o-proj)
// ---------------------------------------------------------------------------
extern "C" void kernel_launch(void* const* d_in, const int* in_sizes, int n_in,
                              void* d_out, int out_size, void* d_ws, size_t ws_size,
                              hipStream_t stream) {
    const float* x = (const float*)d_in[0];
    TTPtrs P;
    const float* biases[4];
    const int base[4] = {2, 7, 12, 17};  // q, k, v, o parameter groups
    for (int t = 0; t < 4; t++) {
        P.c0[t] = (const float*)d_in[base[t] + 0];
        P.c1[t] = (const float*)d_in[base[t] + 1];
        P.c2[t] = (const float*)d_in[base[t] + 2];
        P.c3[t] = (const float*)d_in[base[t] + 3];
        biases[t] = (const float*)d_in[base[t] + 4];
    }

    char* ws = (char*)d_ws;
    float* wsA = (float*)(ws + 0);
    float* wsB = (float*)(ws + 262144);
    uint16_t* Wbf = (uint16_t*)(ws + 4980736);
    uint16_t* xbf = (uint16_t*)(ws + 9699328);
    uint16_t* pO2 = (uint16_t*)(ws + 9699328);     // overlaps xbf (dead by attn)
    float* tbuf = (float*)(ws + 12845056);
    uint16_t* Qbf = (uint16_t*)(ws + 15990784);
    uint16_t* Kbf = (uint16_t*)(ws + 22282240);
    uint16_t* Vtbf = (uint16_t*)(ws + 28573696);
    uint16_t* Obf = (uint16_t*)(ws + 34865152);
    uint16_t* pO1 = (uint16_t*)d_out;              // d_out scratch (rewritten by o-proj)
    (void)Kbf;

    pre_kernel<<<dim3(256 + 3072), 256, 0, stream>>>(P, wsA, x, xbf);
    tt_buildB<<<dim3(1152, 4), 256, 0, stream>>>(P, wsA, wsB);
    tt_buildC<<<dim3(256, 4), 256, 0, stream>>>(P, wsB, Wbf);

    // q, k projections (bf16, row-major); v written transposed to Vtbf
    gemm_mfma<1><<<dim3(32, 6, 3), 256, 0, stream>>>(xbf, Wbf, biases[0], biases[1],
                                                     biases[2], (void*)Qbf, Vtbf);
    // chunked causal attention (QBLK=64) -> partials, then combine -> Obf
    attn_mfma<<<dim3(1920), 256, 0, stream>>>(Qbf, Kbf, Vtbf, pO1, pO2, tbuf);
    attn_combine<<<dim3(768), 256, 0, stream>>>(pO1, pO2, tbuf, Obf);

    // output projection (fp32 out -> d_out)
    gemm_mfma<0><<<dim3(32, 6, 1), 256, 0, stream>>>(Obf, Wbf + 3 * (size_t)W_ELEMS,
                                                     biases[3], biases[3], biases[3],
                                                     d_out, nullptr);
}

// Round 11
// 229.994 us; speedup vs baseline: 1.1354x; 1.0338x over previous
//
#include <hip/hip_runtime.h>
#include <cstddef>
#include <cstdint>

// Problem constants
#define D_MODEL 768
#define N_HEADS 12
#define SEQ 2048
#define BATCH 2
#define NROWS (BATCH * SEQ)          // 4096
#define W_ELEMS (D_MODEL * D_MODEL)  // 589824
#define Y_ELEMS (NROWS * D_MODEL)    // 3145728

typedef __attribute__((ext_vector_type(8))) short bf16x8;
typedef __attribute__((ext_vector_type(4))) float f32x4;

struct TTPtrs {
    const float* c0[4];
    const float* c1[4];
    const float* c2[4];
    const float* c3[4];
};

__device__ __forceinline__ float bf2f(uint16_t u) {
    union { uint32_t u; float f; } c; c.u = ((uint32_t)u) << 16; return c.f;
}
__device__ __forceinline__ uint16_t f2bf(float f) {
    union { float f; uint32_t u; } c; c.f = f;
    uint32_t x = c.u + 0x7fffu + ((c.u >> 16) & 1u);   // RNE
    return (uint16_t)(x >> 16);
}
__device__ __forceinline__ uint32_t cvtpk(float lo, float hi) {
    uint32_t r;
    asm("v_cvt_pk_bf16_f32 %0, %1, %2" : "=v"(r) : "v"(lo), "v"(hi));
    return r;
}
__device__ __forceinline__ void glds16(const void* g, void* l) {
    auto gp = reinterpret_cast<const __attribute__((address_space(1))) uint32_t*>(
        reinterpret_cast<uintptr_t>(g));
    auto lp = reinterpret_cast<__attribute__((address_space(3))) uint32_t*>(
        reinterpret_cast<uintptr_t>(l));
    __builtin_amdgcn_global_load_lds(gp, lp, 16, 0, 0);
}

// ---------------------------------------------------------------------------
// wbuild: ENTIRE TT weight build fused into one kernel (was 3: buildA/B/C with
// wsA/wsB HBM round-trips) + x->bf16 conversion (blocks >= 1024).
// Block (mat, mipj): A-row (64 f32) -> B-slice [36][32] (LDS, padded 33)
// -> 48x48 W-patch, all in-LDS. Wbf[mat][out][in] bf16.
// ---------------------------------------------------------------------------
__global__ __launch_bounds__(256) void wbuild(TTPtrs P, uint16_t* __restrict__ Wbf,
                                              const float* __restrict__ x,
                                              uint16_t* __restrict__ xb) {
    __shared__ float c_lds[2048];      // c3 [t][ul]
    __shared__ float a_lds[64];        // A-row [s]
    __shared__ float b_lds[36 * 33];   // B-slice [qk][t], stride 33
    const int bx = blockIdx.x;
    const int tid = threadIdx.x;
    if (bx >= 1024) {                  // x -> bf16 part
        int idx = ((bx - 1024) * 256 + tid) * 4;
        float4 v = *(const float4*)(x + idx);
        *(uint2*)(xb + idx) = make_uint2(cvtpk(v.x, v.y), cvtpk(v.z, v.w));
        return;
    }
    const int mat = bx >> 8, mipj = bx & 255;
    const int mi = mipj >> 4, pj = mipj & 15;
    const int m = mi >> 2, i = mi & 3, p = pj >> 2, j = pj & 3;
    const float* c2 = P.c2[mat];
    uint16_t* Wt = Wbf + (size_t)mat * W_ELEMS;

    for (int e = tid; e < 2048; e += 256)
        c_lds[e] = P.c3[mat][e];
    if (tid < 64) {                    // A[s] = sum_r c0[mi][r] * c1[r][pj][s]
        const float* c0 = P.c0[mat];
        const float* c1 = P.c1[mat];
        float acc = 0.f;
        #pragma unroll 8
        for (int r = 0; r < 32; r++)
            acc = fmaf(c0[mi * 32 + r], c1[(r * 16 + pj) * 64 + tid], acc);
        a_lds[tid] = acc;
    }
    __syncthreads();

    // B[qk][t] = sum_s A[s] * c2[s][qk][t]; idx coalesced across threads
    #pragma unroll
    for (int n = 0; n < 5; ++n) {
        int idx = n * 256 + tid;
        if (idx < 1152) {
            float acc = 0.f;
            #pragma unroll 8
            for (int s = 0; s < 64; s++)
                acc = fmaf(a_lds[s], c2[s * 1152 + idx], acc);
            b_lds[(idx >> 5) * 33 + (idx & 31)] = acc;
        }
    }
    __syncthreads();

    // W-patch: 2304 outputs, 9/thread
    const int outbase = (m * 4 + p) * 48;
    const int inbase = (i * 4 + j) * 48;
    #pragma unroll
    for (int n = 0; n < 9; n++) {
        int idx = n * 256 + tid;
        int qu = idx / 48, kl = idx % 48;
        int q = qu >> 3, u = qu & 7, k = kl >> 3, l = kl & 7;
        const float* brow = &b_lds[(q * 6 + k) * 33];
        const float* crow = &c_lds[u * 8 + l];
        float acc = 0.f;
        #pragma unroll 8
        for (int t = 0; t < 32; t++)
            acc = fmaf(brow[t], crow[t * 64], acc);
        Wt[(size_t)(outbase + qu) * D_MODEL + inbase + kl] = f2bf(acc);
    }
}

// ---------------------------------------------------------------------------
// bf16 MFMA GEMM. MODE 0: f32 out. MODE 1: bf16 out; z==2 writes V transposed
// to Vt[b][h][d][s] via LDS-transpose.
// ---------------------------------------------------------------------------
template <int MODE>
__global__ __launch_bounds__(256) void gemm_mfma(const uint16_t* __restrict__ X,
                                                 const uint16_t* __restrict__ Wall,
                                                 const float* __restrict__ b0,
                                                 const float* __restrict__ b1,
                                                 const float* __restrict__ b2,
                                                 void* __restrict__ Yall,
                                                 uint16_t* __restrict__ Vt) {
    __shared__ uint16_t lds[2][8192];
    const int z = blockIdx.z;
    const uint16_t* W = Wall + (size_t)z * W_ELEMS;
    const float* bias = (z == 0) ? b0 : (z == 1 ? b1 : b2);
    const int m0 = blockIdx.x * 128, n0 = blockIdx.y * 128;
    const int tid = threadIdx.x, w = tid >> 6, l = tid & 63;
    const int wr = w >> 1, wc = w & 1;
    const int l15 = l & 15, lg = l >> 4;

    const int srow = w * 32 + (l >> 2);
    const int scol = ((l & 3) ^ ((l >> 2) & 3)) * 8;
    const uint16_t* Abase = X + (size_t)(m0 + srow) * D_MODEL + scol;
    const uint16_t* Bbase = W + (size_t)(n0 + srow) * D_MODEL + scol;

    f32x4 acc[4][4];
    #pragma unroll
    for (int mi = 0; mi < 4; ++mi)
        #pragma unroll
        for (int ni = 0; ni < 4; ++ni) acc[mi][ni] = (f32x4){0.f, 0.f, 0.f, 0.f};

    auto stage = [&](int buf, int kt) {
        const uint16_t* A0 = Abase + kt * 32;
        const uint16_t* B0 = Bbase + kt * 32;
        glds16(A0, &lds[buf][w * 1024]);
        glds16(A0 + 16 * D_MODEL, &lds[buf][w * 1024 + 512]);
        glds16(B0, &lds[buf][4096 + w * 1024]);
        glds16(B0 + 16 * D_MODEL, &lds[buf][4096 + w * 1024 + 512]);
    };

    stage(0, 0);
    __syncthreads();
    const int roff = ((lg ^ (l & 3)) << 3);
    for (int kt = 0; kt < 24; ++kt) {
        int cur = kt & 1;
        if (kt < 23) stage(cur ^ 1, kt + 1);
        const uint16_t* As = &lds[cur][0];
        const uint16_t* Bs = &lds[cur][4096];
        bf16x8 a[4], bb[4];
        #pragma unroll
        for (int mi = 0; mi < 4; ++mi)
            a[mi] = *(const bf16x8*)(As + (wr * 64 + mi * 16 + l15) * 32 + roff);
        #pragma unroll
        for (int ni = 0; ni < 4; ++ni)
            bb[ni] = *(const bf16x8*)(Bs + (wc * 64 + ni * 16 + l15) * 32 + roff);
        #pragma unroll
        for (int mi = 0; mi < 4; ++mi)
            #pragma unroll
            for (int ni = 0; ni < 4; ++ni)
                acc[mi][ni] = __builtin_amdgcn_mfma_f32_16x16x32_bf16(
                    a[mi], bb[ni], acc[mi][ni], 0, 0, 0);
        __syncthreads();
    }

    float bv[4];
    #pragma unroll
    for (int ni = 0; ni < 4; ++ni) bv[ni] = bias[n0 + wc * 64 + ni * 16 + l15];

    if (MODE == 1 && z == 2) {
        // V^T via LDS transpose (XOR-swizzled), 128B-contiguous stores.
        uint16_t* T = &lds[0][0];
        #pragma unroll
        for (int mi = 0; mi < 4; ++mi) {
            int row = wr * 64 + mi * 16 + lg * 4;
            #pragma unroll
            for (int ni = 0; ni < 4; ++ni) {
                int col = wc * 64 + ni * 16 + l15;
                float v0 = acc[mi][ni][0] + bv[ni], v1 = acc[mi][ni][1] + bv[ni];
                float v2 = acc[mi][ni][2] + bv[ni], v3 = acc[mi][ni][3] + bv[ni];
                int byte = (col << 8) + (row << 1);
                byte ^= (((col & 31) ^ (row >> 6)) << 3);
                *(uint2*)((char*)T + byte) = make_uint2(cvtpk(v0, v1), cvtpk(v2, v3));
            }
        }
        __syncthreads();
        int col = tid >> 1, half = tid & 1;
        int gcol = n0 + col;
        int bb_ = m0 >> 11;
        int s = (m0 & 2047) + half * 64;
        uint16_t* dst = Vt + ((size_t)(bb_ * 12 + (gcol >> 6)) * 64 + (gcol & 63)) * 2048 + s;
        uint2 tv[16];
        #pragma unroll
        for (int k = 0; k < 16; ++k) {
            int r = half * 64 + k * 4;
            int byte = (col << 8) + (r << 1);
            byte ^= (((col & 31) ^ (r >> 6)) << 3);
            tv[k] = *(const uint2*)((const char*)T + byte);
        }
        #pragma unroll
        for (int k = 0; k < 8; ++k)
            *(uint4*)(dst + k * 8) = make_uint4(tv[2 * k].x, tv[2 * k].y,
                                                tv[2 * k + 1].x, tv[2 * k + 1].y);
    } else {
        #pragma unroll
        for (int mi = 0; mi < 4; ++mi)
            #pragma unroll
            for (int ni = 0; ni < 4; ++ni)
                #pragma unroll
                for (int r = 0; r < 4; ++r) {
                    int row = m0 + wr * 64 + mi * 16 + lg * 4 + r;
                    int col = n0 + wc * 64 + ni * 16 + l15;
                    float v = acc[mi][ni][r] + bv[ni];
                    if (MODE == 1)
                        ((uint16_t*)Yall + (size_t)z * Y_ELEMS)[(size_t)row * D_MODEL + col] = f2bf(v);
                    else
                        ((float*)Yall)[(size_t)row * D_MODEL + col] = v;
                }
    }
}

// ---------------------------------------------------------------------------
// Chunked causal flash attention, QBLK=64 (52-VGPR; QBLK=128 regressed: 116
// VGPR, MfmaUtil 6.5%, +43us). Key-split: chunk = up to 8 key-tiles of one
// (bh, qt); 80 units/bh, big chunks first; grid 1920. Writes NORMALIZED
// partial O (bf16) + per-q combine weight t = m + log2(l).
// ---------------------------------------------------------------------------
__global__ __launch_bounds__(256) void attn_mfma(const uint16_t* __restrict__ Q,
                                                 const uint16_t* __restrict__ K,
                                                 const uint16_t* __restrict__ Vt,
                                                 uint16_t* __restrict__ pO1,
                                                 uint16_t* __restrict__ pO2,
                                                 float* __restrict__ tbuf) {
    __shared__ uint16_t ks[2][4096];
    __shared__ uint16_t vs[2][4096];
    __shared__ uint16_t ps[4][1024];

    const int bx = blockIdx.x;
    const int u = bx / 24;
    const int bh = bx % 24;
    int g, c;
    if (u < 32)      { g = u >> 2,            c = u & 3; }
    else if (u < 56) { int t = u - 32; g = 8 + t / 3,  c = t % 3; }
    else if (u < 72) { int t = u - 56; g = 16 + (t >> 1), c = t & 1; }
    else             { g = 24 + (u - 72),     c = 0; }
    const int qt = 31 - g;
    const int ktlo = c * 8;
    const int kthi = min(ktlo + 7, qt);
    const int nkt = kthi - ktlo + 1;

    const int b = bh / 12, h = bh % 12;
    const int tid = threadIdx.x, w = tid >> 6, l = tid & 63;
    const int l15 = l & 15, lg = l >> 4;
    const size_t headoff = (size_t)b * SEQ * D_MODEL + h * 64;
    const size_t vhead = ((size_t)(b * 12 + h)) << 17;
    const int sc8 = ((l & 7) ^ ((l >> 3) & 7)) * 8;
    const int srow = w * 16 + (l >> 3);

    // Q B-frags, pre-scaled by log2(e)/8 (exp2-domain scores)
    const float QS = 0.125f * 1.44269504088896f;
    bf16x8 qf[2];
    {
        const uint16_t* qp = Q + headoff + (size_t)(qt * 64 + w * 16 + l15) * D_MODEL + lg * 8;
        #pragma unroll
        for (int ds = 0; ds < 2; ++ds) {
            bf16x8 qv = *(const bf16x8*)(qp + ds * 32);
            #pragma unroll
            for (int j = 0; j < 8; ++j)
                qf[ds][j] = (short)f2bf(bf2f((uint16_t)qv[j]) * QS);
        }
    }

    float m_ = -3e38f, l_ = 0.f;
    f32x4 oacc[4];
    #pragma unroll
    for (int ni = 0; ni < 4; ++ni) oacc[ni] = (f32x4){0.f, 0.f, 0.f, 0.f};
    const int qglob = qt * 64 + w * 16 + l15;

    auto stage = [&](int buf, int kt) {
        const uint16_t* ksrc = K + headoff + (size_t)(kt * 64 + srow) * D_MODEL + sc8;
        glds16(ksrc, &ks[buf][w * 1024]);
        glds16(ksrc + 8 * D_MODEL, &ks[buf][w * 1024 + 512]);
        const uint16_t* vsrc = Vt + vhead + (size_t)srow * SEQ + kt * 64 + sc8;
        glds16(vsrc, &vs[buf][w * 1024]);
        glds16(vsrc + 8 * SEQ, &vs[buf][w * 1024 + 512]);
    };

    stage(0, ktlo);
    for (int it = 0; it < nkt; ++it) {
        const int kt = ktlo + it;
        const int cur = it & 1;
        __syncthreads();
        if (it + 1 < nkt) stage(cur ^ 1, kt + 1);

        // S^T[key][q] = K · Qs^T
        f32x4 sacc[4];
        #pragma unroll
        for (int ki = 0; ki < 4; ++ki) sacc[ki] = (f32x4){0.f, 0.f, 0.f, 0.f};
        __builtin_amdgcn_s_setprio(1);
        #pragma unroll
        for (int ds = 0; ds < 2; ++ds)
            #pragma unroll
            for (int ki = 0; ki < 4; ++ki) {
                int byte = (ki * 16 + l15) * 128 + ((((ds << 2) + lg) ^ (l15 & 7)) << 4);
                bf16x8 ak = *(const bf16x8*)((const char*)&ks[cur][0] + byte);
                sacc[ki] = __builtin_amdgcn_mfma_f32_16x16x32_bf16(ak, qf[ds], sacc[ki], 0, 0, 0);
            }
        __builtin_amdgcn_s_setprio(0);

        const bool diag = (kt == qt);
        float sv[16];
        #pragma unroll
        for (int ki = 0; ki < 4; ++ki)
            #pragma unroll
            for (int r = 0; r < 4; ++r) {
                float s = sacc[ki][r];
                if (diag) {
                    int key = kt * 64 + ki * 16 + lg * 4 + r;
                    if (key > qglob) s = -3e38f;
                }
                sv[ki * 4 + r] = s;
            }
        // max tree (max3-fusable)
        float mx = fmaxf(fmaxf(sv[0], sv[1]), sv[2]);
        #pragma unroll
        for (int i = 3; i < 15; i += 2) mx = fmaxf(fmaxf(mx, sv[i]), sv[i + 1]);
        mx = fmaxf(mx, sv[15]);
        mx = fmaxf(mx, __shfl_xor(mx, 16));
        mx = fmaxf(mx, __shfl_xor(mx, 32));
        if (__any(mx > m_ + 11.54f)) {         // defer-max (T13), log2 units
            float mnew = fmaxf(m_, mx);
            float alpha = __builtin_amdgcn_exp2f(m_ - mnew);
            l_ *= alpha;
            float a0 = __shfl(alpha, lg * 4 + 0), a1 = __shfl(alpha, lg * 4 + 1);
            float a2 = __shfl(alpha, lg * 4 + 2), a3 = __shfl(alpha, lg * 4 + 3);
            #pragma unroll
            for (int ni = 0; ni < 4; ++ni) {
                oacc[ni][0] *= a0; oacc[ni][1] *= a1;
                oacc[ni][2] *= a2; oacc[ni][3] *= a3;
            }
            m_ = mnew;
        }
        float sum = 0.f;
        uint32_t pk[8];
        #pragma unroll
        for (int i = 0; i < 16; i += 2) {
            float p0 = __builtin_amdgcn_exp2f(sv[i] - m_);
            float p1 = __builtin_amdgcn_exp2f(sv[i + 1] - m_);
            sum += p0 + p1;
            pk[i >> 1] = cvtpk(p0, p1);
        }
        sum += __shfl_xor(sum, 16);
        sum += __shfl_xor(sum, 32);
        l_ += sum;

        uint16_t* psw = &ps[w][0];
        #pragma unroll
        for (int ki = 0; ki < 4; ++ki) {
            int byte = (l15 * 128 + ki * 32 + lg * 8) ^ ((l15 & 7) << 4);
            *(uint2*)((char*)psw + byte) = make_uint2(pk[ki * 2], pk[ki * 2 + 1]);
        }
        asm volatile("s_waitcnt lgkmcnt(0)" ::: "memory");
        __builtin_amdgcn_sched_barrier(0);

        __builtin_amdgcn_s_setprio(1);
        #pragma unroll
        for (int kss = 0; kss < 2; ++kss) {
            int pbyte = l15 * 128 + ((((kss << 2) + lg) ^ (l15 & 7)) << 4);
            bf16x8 ap = *(const bf16x8*)((const char*)psw + pbyte);
            #pragma unroll
            for (int ni = 0; ni < 4; ++ni) {
                int vbyte = (ni * 16 + l15) * 128 + ((((kss << 2) + lg) ^ (l15 & 7)) << 4);
                bf16x8 bv = *(const bf16x8*)((const char*)&vs[cur][0] + vbyte);
                oacc[ni] = __builtin_amdgcn_mfma_f32_16x16x32_bf16(ap, bv, oacc[ni], 0, 0, 0);
            }
        }
        __builtin_amdgcn_s_setprio(0);
    }

    // Epilogue: normalized partial O (bf16) + combine weight t = m + log2(l)
    float li0 = 1.f / __shfl(l_, lg * 4 + 0), li1 = 1.f / __shfl(l_, lg * 4 + 1);
    float li2 = 1.f / __shfl(l_, lg * 4 + 2), li3 = 1.f / __shfl(l_, lg * 4 + 3);
    uint16_t* op = (bx < 1536) ? (pO1 + (size_t)bx * 4096)
                               : (pO2 + (size_t)(bx - 1536) * 4096);
    #pragma unroll
    for (int ni = 0; ni < 4; ++ni) {
        int col = ni * 16 + l15;
        int rbase = (w * 16 + lg * 4) * 64 + col;
        op[rbase + 0 * 64] = f2bf(oacc[ni][0] * li0);
        op[rbase + 1 * 64] = f2bf(oacc[ni][1] * li1);
        op[rbase + 2 * 64] = f2bf(oacc[ni][2] * li2);
        op[rbase + 3 * 64] = f2bf(oacc[ni][3] * li3);
    }
    if (lg == 0)
        tbuf[(size_t)bx * 64 + w * 16 + l15] = m_ + __log2f(l_);
}

// ---------------------------------------------------------------------------
// Combine partial chunks per (bh, qt): O = sum_c 2^(t_c - tmax) * Ohat_c / denom.
// Grid 768 blocks; thread -> (q = tid/4, d-range = (tid&3)*16 .. +15).
// ---------------------------------------------------------------------------
__global__ __launch_bounds__(256) void attn_combine(const uint16_t* __restrict__ pO1,
                                                    const uint16_t* __restrict__ pO2,
                                                    const float* __restrict__ tbuf,
                                                    uint16_t* __restrict__ Obf) {
    __shared__ float t_lds[4][64];
    const int bx = blockIdx.x;
    const int qt = bx & 31, bh = bx >> 5;
    const int b = bh / 12, h = bh % 12;
    const int g = 31 - qt;
    const int u_base = (g < 8) ? 4 * g : (g < 16) ? 32 + 3 * (g - 8)
                     : (g < 24) ? 56 + 2 * (g - 16) : 72 + (g - 24);
    const int nc = (g < 8) ? 4 : (g < 16) ? 3 : (g < 24) ? 2 : 1;
    const int tid = threadIdx.x;
    if (tid < nc * 64) {
        int c = tid >> 6, q = tid & 63;
        t_lds[c][q] = tbuf[(size_t)((u_base + c) * 24 + bh) * 64 + q];
    }
    __syncthreads();

    const int q = tid >> 2, d0 = (tid & 3) * 16;
    float tmax = t_lds[0][q];
    for (int c = 1; c < nc; ++c) tmax = fmaxf(tmax, t_lds[c][q]);
    float acc[16];
    #pragma unroll
    for (int j = 0; j < 16; ++j) acc[j] = 0.f;
    float denom = 0.f;
    for (int c = 0; c < nc; ++c) {
        float wgt = __builtin_amdgcn_exp2f(t_lds[c][q] - tmax);
        denom += wgt;
        int ug = (u_base + c) * 24 + bh;
        const uint16_t* op = (ug < 1536) ? (pO1 + (size_t)ug * 4096)
                                         : (pO2 + (size_t)(ug - 1536) * 4096);
        bf16x8 v0 = *(const bf16x8*)(op + q * 64 + d0);
        bf16x8 v1 = *(const bf16x8*)(op + q * 64 + d0 + 8);
        #pragma unroll
        for (int j = 0; j < 8; ++j) {
            acc[j]     += bf2f((uint16_t)v0[j]) * wgt;
            acc[8 + j] += bf2f((uint16_t)v1[j]) * wgt;
        }
    }
    float inv = 1.f / denom;
    uint32_t outp[8];
    #pragma unroll
    for (int j = 0; j < 8; ++j)
        outp[j] = cvtpk(acc[2 * j] * inv, acc[2 * j + 1] * inv);
    size_t rb = (size_t)(b * SEQ + qt * 64 + q) * D_MODEL + h * 64 + d0;
    *(uint4*)(Obf + rb)     = make_uint4(outp[0], outp[1], outp[2], outp[3]);
    *(uint4*)(Obf + rb + 8) = make_uint4(outp[4], outp[5], outp[6], outp[7]);
}

// ---------------------------------------------------------------------------
// Workspace (bytes):
//   Wbf @ 4980736 (4718592) bf16 [4][out][in]
//   xbf @ 9699328 (6291456) [dead after gemm<1>] -> partial units 1536..1919
//   tbuf @ 12845056 (491520)
//   Qbf @ 15990784 | Kbf @ 22282240 | Vtbf @ 28573696 | Obf @ 34865152
//   d_out (12582912 B) = partial units 0..1535 (fully overwritten by o-proj)
// ---------------------------------------------------------------------------
extern "C" void kernel_launch(void* const* d_in, const int* in_sizes, int n_in,
                              void* d_out, int out_size, void* d_ws, size_t ws_size,
                              hipStream_t stream) {
    const float* x = (const float*)d_in[0];
    TTPtrs P;
    const float* biases[4];
    const int base[4] = {2, 7, 12, 17};  // q, k, v, o parameter groups
    for (int t = 0; t < 4; t++) {
        P.c0[t] = (const float*)d_in[base[t] + 0];
        P.c1[t] = (const float*)d_in[base[t] + 1];
        P.c2[t] = (const float*)d_in[base[t] + 2];
        P.c3[t] = (const float*)d_in[base[t] + 3];
        biases[t] = (const float*)d_in[base[t] + 4];
    }

    char* ws = (char*)d_ws;
    uint16_t* Wbf = (uint16_t*)(ws + 4980736);
    uint16_t* xbf = (uint16_t*)(ws + 9699328);
    uint16_t* pO2 = (uint16_t*)(ws + 9699328);     // overlaps xbf (dead by attn)
    float* tbuf = (float*)(ws + 12845056);
    uint16_t* Qbf = (uint16_t*)(ws + 15990784);
    uint16_t* Kbf = (uint16_t*)(ws + 22282240);
    uint16_t* Vtbf = (uint16_t*)(ws + 28573696);
    uint16_t* Obf = (uint16_t*)(ws + 34865152);
    uint16_t* pO1 = (uint16_t*)d_out;              // d_out scratch (rewritten by o-proj)
    (void)Kbf;

    // fused weight build + x->bf16 (1 launch; was 3)
    wbuild<<<dim3(1024 + 3072), 256, 0, stream>>>(P, Wbf, x, xbf);

    // q, k projections (bf16, row-major); v written transposed to Vtbf
    gemm_mfma<1><<<dim3(32, 6, 3), 256, 0, stream>>>(xbf, Wbf, biases[0], biases[1],
                                                     biases[2], (void*)Qbf, Vtbf);
    // chunked causal attention (QBLK=64) -> partials, then combine -> Obf
    attn_mfma<<<dim3(1920), 256, 0, stream>>>(Qbf, Kbf, Vtbf, pO1, pO2, tbuf);
    attn_combine<<<dim3(768), 256, 0, stream>>>(pO1, pO2, tbuf, Obf);

    // output projection (fp32 out -> d_out)
    gemm_mfma<0><<<dim3(32, 6, 1), 256, 0, stream>>>(Obf, Wbf + 3 * (size_t)W_ELEMS,
                                                     biases[3], biases[3], biases[3],
                                                     d_out, nullptr);
}